// Round 3
// baseline (524.518 us; speedup 1.0000x reference)
//
#include <hip/hip_runtime.h>
#include <hip/hip_bf16.h>

// Problem constants
#define B_TOT  4096
#define M_TOT  65536
#define D_V    64
#define KD     96            // 64 (keys) + 32 (0.5*contexts), both pre-scaled by log2e
#define BQ     64            // q rows per block (4 waves x 16)
#define BN     64            // keys per inner tile
#define NQT    (B_TOT / BQ)  // 64
#define SP     72            // padded LDS row stride (bf16 elems), 144B, 16B-aligned rows
#define SHIFT2 23.0f         // fixed softmax shift in exp2 domain

using short8  = __attribute__((ext_vector_type(8))) short;
using floatx4 = __attribute__((ext_vector_type(4))) float;

static __device__ __forceinline__ unsigned short f2bf(float f) {
  return __builtin_bit_cast(unsigned short, __float2bfloat16(f));
}

static __device__ __forceinline__ floatx4 mfma16(short8 a, short8 b, floatx4 c) {
  return __builtin_amdgcn_mfma_f32_16x16x32_bf16(a, b, c, 0, 0, 0);
}

#define LOG2E 1.4426950408889634f

// ---- prep kernels -----------------------------------------------------------

__global__ void prep_qc(const float* __restrict__ q, const float* __restrict__ ctx,
                        unsigned short* __restrict__ qc) {
  int t = blockIdx.x * 256 + threadIdx.x;      // 4096*96 total
  int b = t / KD, j = t % KD;
  float v = (j < 64) ? q[b * 64 + j] : 0.5f * ctx[b * 32 + (j - 64)];
  qc[t] = f2bf(v * LOG2E);                     // fold log2(e) for exp2 softmax
}

__global__ void prep_kc(const float* __restrict__ k, const float* __restrict__ c,
                        unsigned short* __restrict__ kc) {
  int t = blockIdx.x * 256 + threadIdx.x;      // 65536*96 total
  int m = t / KD, j = t % KD;
  float v = (j < 64) ? k[m * 64 + j] : c[m * 32 + (j - 64)];
  kc[t] = f2bf(v);
}

__global__ void prep_bias(const float* __restrict__ ts, const int* __restrict__ used,
                          float* __restrict__ bias) {
  int m = blockIdx.x * 256 + threadIdx.x;
  // exp2 domain: log2e*(0.3*decay) - SHIFT2 ; masked -> -1e9 (exp2 -> 0)
  bias[m] = used[m] ? (LOG2E * 0.3f * __expf(-0.1f * (1.0f - ts[m])) - SHIFT2) : -1e9f;
}

// V repacked into per-tile layout: vt[g][d(64)][n(64)], g = m/64, n = m%64
__global__ void prep_vt(const float* __restrict__ v, unsigned short* __restrict__ vt) {
  __shared__ float tile[64][65];
  int g = blockIdx.x;
  int m0 = g * 64;
  int t = threadIdx.x;
#pragma unroll
  for (int i = 0; i < 16; ++i) {
    int idx = i * 256 + t;
    int r = idx >> 6, cc = idx & 63;
    tile[r][cc] = v[(size_t)(m0 + r) * 64 + cc];
  }
  __syncthreads();
  unsigned short* outp = vt + (size_t)g * 4096;
#pragma unroll
  for (int i = 0; i < 16; ++i) {
    int idx = i * 256 + t;
    int d = idx >> 6, n = idx & 63;
    outp[idx] = f2bf(tile[n][d]);
  }
}

// ---- flash attention main kernel -------------------------------------------
// grid (NQT, NC); block 256 = 4 waves, each wave owns 16 q-rows.
// Fixed-shift softmax: P = exp2(S + bias'); partials combine linearly.

template<int NC>
__global__ __launch_bounds__(256, 8) void
flash_kernel(const unsigned short* __restrict__ qc,
             const unsigned short* __restrict__ kc,
             const unsigned short* __restrict__ vt,
             const float* __restrict__ bias,
             float* __restrict__ opart, float* __restrict__ lpart)
{
  constexpr int MC = M_TOT / NC;
  __shared__ __align__(16) unsigned short pt[4][16][SP];  // per-wave P tiles
  const int qt    = blockIdx.x;
  const int chunk = blockIdx.y;
  const int tid   = threadIdx.x;
  const int w     = tid >> 6;
  const int lane  = tid & 63;
  const int lq    = lane >> 4;   // quad
  const int lc    = lane & 15;

  floatx4 zero; zero[0] = 0.f; zero[1] = 0.f; zero[2] = 0.f; zero[3] = 0.f;

  // Q fragments (A-layout: m=lc, k = ks*32 + lq*8 + j), contiguous 16B loads
  const int qrow = qt * BQ + w * 16 + lc;
  const unsigned short* qrp = qc + (size_t)qrow * KD + lq * 8;
  short8 qf0 = *reinterpret_cast<const short8*>(qrp);
  short8 qf1 = *reinterpret_cast<const short8*>(qrp + 32);
  short8 qf2 = *reinterpret_cast<const short8*>(qrp + 64);

  short8 ones;
#pragma unroll
  for (int i = 0; i < 8; ++i) ones[i] = (short)0x3F80;  // bf16 1.0

  // base pointers (lane-resolved); all per-iter variation via constant offsets
  const unsigned short* kptr = kc + (size_t)(chunk * MC) * KD + lc * KD + lq * 8;
  const unsigned short* vptr = vt + (size_t)(chunk * (MC / 64)) * 4096 + lc * 64 + lq * 8;
  const float* bptr = bias + chunk * MC + lc;

  floatx4 o0 = zero, o1 = zero, o2 = zero, o3 = zero;
  floatx4 lacc = zero;

  // per-wave LDS addresses (constant across iters)
  unsigned short* wrow = &pt[w][0][0];

#pragma unroll 2
  for (int it = 0; it < MC / BN; ++it) {
    // ---- S = Q * K^T and P = exp2(S + bias'), per 16-key tile ----
#pragma unroll
    for (int nt = 0; nt < 4; ++nt) {
      short8 k0 = *reinterpret_cast<const short8*>(kptr + nt * 16 * KD);
      short8 k1 = *reinterpret_cast<const short8*>(kptr + nt * 16 * KD + 32);
      short8 k2 = *reinterpret_cast<const short8*>(kptr + nt * 16 * KD + 64);
      floatx4 acc = zero;
      acc = mfma16(qf0, k0, acc);
      acc = mfma16(qf1, k1, acc);
      acc = mfma16(qf2, k2, acc);
      float badj = bptr[nt * 16];
#pragma unroll
      for (int r = 0; r < 4; ++r) {
        float p = __builtin_amdgcn_exp2f(acc[r] + badj);
        wrow[(lq * 4 + r) * SP + nt * 16 + lc] = f2bf(p);
      }
    }
    // ---- P back out in A-layout (row = lc, k contiguous); same-wave DS order ----
    short8 pa0 = *reinterpret_cast<const short8*>(wrow + lc * SP + lq * 8);
    short8 pa1 = *reinterpret_cast<const short8*>(wrow + lc * SP + 32 + lq * 8);
    // row sums via ones-MFMA
    lacc = mfma16(pa0, ones, lacc);
    lacc = mfma16(pa1, ones, lacc);
    // ---- O += P * V (B-frag = contiguous run of a V-tile row) ----
    {
      short8 v00 = *reinterpret_cast<const short8*>(vptr);
      short8 v01 = *reinterpret_cast<const short8*>(vptr + 32);
      o0 = mfma16(pa0, v00, o0);  o0 = mfma16(pa1, v01, o0);
      short8 v10 = *reinterpret_cast<const short8*>(vptr + 1024);
      short8 v11 = *reinterpret_cast<const short8*>(vptr + 1056);
      o1 = mfma16(pa0, v10, o1);  o1 = mfma16(pa1, v11, o1);
      short8 v20 = *reinterpret_cast<const short8*>(vptr + 2048);
      short8 v21 = *reinterpret_cast<const short8*>(vptr + 2080);
      o2 = mfma16(pa0, v20, o2);  o2 = mfma16(pa1, v21, o2);
      short8 v30 = *reinterpret_cast<const short8*>(vptr + 3072);
      short8 v31 = *reinterpret_cast<const short8*>(vptr + 3104);
      o3 = mfma16(pa0, v30, o3);  o3 = mfma16(pa1, v31, o3);
    }
    kptr += BN * KD;
    vptr += 4096;
    bptr += BN;
  }

  // epilogue: write partial O and l
  const int pb = qt * NC + chunk;
  float* op = opart + (size_t)pb * BQ * D_V;
  const int rbase = w * 16 + lq * 4;
  floatx4 oo[4] = {o0, o1, o2, o3};
#pragma unroll
  for (int nd = 0; nd < 4; ++nd)
#pragma unroll
    for (int r = 0; r < 4; ++r)
      op[(rbase + r) * D_V + nd * 16 + lc] = oo[nd][r];
  if (lc == 0) {
    float* lp = lpart + (size_t)pb * BQ;
#pragma unroll
    for (int r = 0; r < 4; ++r) lp[rbase + r] = lacc[r];
  }
}

// ---- final reduction --------------------------------------------------------

template<int NC>
__global__ void reduce_out(const float* __restrict__ opart, const float* __restrict__ lpart,
                           float* __restrict__ out) {
  int t = blockIdx.x * 256 + threadIdx.x;   // 262144 total
  int b = t >> 6, d = t & 63;
  int qt = b >> 6, r = b & 63;
  float os = 0.f, ls = 0.f;
#pragma unroll
  for (int c = 0; c < NC; ++c) {
    os += opart[((size_t)(qt * NC + c) * BQ + r) * D_V + d];
    ls += lpart[(size_t)(qt * NC + c) * BQ + r];
  }
  out[t] = os / ls;
}

// ---- launcher ---------------------------------------------------------------

template<int NC>
static void launch_all(const float* query, const float* context, const float* keys,
                       const float* values, const float* contexts, const float* ts,
                       const int* used, float* out, char* ws, hipStream_t stream) {
  unsigned short* qc = (unsigned short*)ws;  ws += (size_t)B_TOT * KD * 2;      // 768 KB
  unsigned short* kc = (unsigned short*)ws;  ws += (size_t)M_TOT * KD * 2;      // 12 MB
  unsigned short* vt = (unsigned short*)ws;  ws += (size_t)D_V * M_TOT * 2;     // 8 MB
  float* bias  = (float*)ws;                 ws += (size_t)M_TOT * 4;           // 256 KB
  float* opart = (float*)ws;                 ws += (size_t)NC * B_TOT * D_V * 4;
  float* lpart = (float*)ws;

  prep_qc  <<<(B_TOT * KD) / 256, 256, 0, stream>>>(query, context, qc);
  prep_kc  <<<(M_TOT * KD) / 256, 256, 0, stream>>>(keys, contexts, kc);
  prep_bias<<<M_TOT / 256,        256, 0, stream>>>(ts, used, bias);
  prep_vt  <<<M_TOT / 64,         256, 0, stream>>>(values, vt);

  dim3 grid(NQT, NC);
  flash_kernel<NC><<<grid, 256, 0, stream>>>(qc, kc, vt, bias, opart, lpart);

  reduce_out<NC><<<(B_TOT * D_V) / 256, 256, 0, stream>>>(opart, lpart, out);
}

extern "C" void kernel_launch(void* const* d_in, const int* in_sizes, int n_in,
                              void* d_out, int out_size, void* d_ws, size_t ws_size,
                              hipStream_t stream) {
  const float* query    = (const float*)d_in[0];
  const float* context  = (const float*)d_in[1];
  const float* keys     = (const float*)d_in[2];
  const float* values   = (const float*)d_in[3];
  const float* contexts = (const float*)d_in[4];
  const float* ts       = (const float*)d_in[5];
  const int*   used     = (const int*)d_in[6];
  float* out = (float*)d_out;
  char* ws = (char*)d_ws;

  // fixed prefix: qc + kc + vt + bias = 21.25 MB; partials: NC*(1 MB + 16 KB)
  const size_t fixed = (size_t)B_TOT * KD * 2 + (size_t)M_TOT * KD * 2 +
                       (size_t)D_V * M_TOT * 2 + (size_t)M_TOT * 4;
  const size_t need32 = fixed + 32ull * ((size_t)B_TOT * D_V * 4 + (size_t)B_TOT * 4);

  if (ws_size >= need32)
    launch_all<32>(query, context, keys, values, contexts, ts, used, out, ws, stream);
  else
    launch_all<16>(query, context, keys, values, contexts, ts, used, out, ws, stream);
}

// Round 4
// 226.178 us; speedup vs baseline: 2.3191x; 2.3191x over previous
//
#include <hip/hip_runtime.h>
#include <hip/hip_bf16.h>

// Problem constants
#define B_TOT  4096
#define M_TOT  65536
#define D_V    64
#define KD     96            // 64 (keys) + 32 (0.5*contexts); Q side pre-scaled by log2e
#define BQ     128           // q rows per block (4 waves x 32)
#define BN     64            // keys per inner tile
#define NQT    (B_TOT / BQ)  // 32
#define SP     72            // padded LDS row stride (bf16 elems), 144B, 16B-aligned rows
#define SHIFT2 23.0f         // fixed softmax shift in exp2 domain

using short8  = __attribute__((ext_vector_type(8))) short;
using floatx4 = __attribute__((ext_vector_type(4))) float;

static __device__ __forceinline__ unsigned short f2bf(float f) {
  return __builtin_bit_cast(unsigned short, __float2bfloat16(f));
}

static __device__ __forceinline__ floatx4 mfma16(short8 a, short8 b, floatx4 c) {
  return __builtin_amdgcn_mfma_f32_16x16x32_bf16(a, b, c, 0, 0, 0);
}

#define LOG2E 1.4426950408889634f

// ---- prep kernels -----------------------------------------------------------

__global__ void prep_qc(const float* __restrict__ q, const float* __restrict__ ctx,
                        unsigned short* __restrict__ qc) {
  int t = blockIdx.x * 256 + threadIdx.x;      // 4096*96 total
  int b = t / KD, j = t % KD;
  float v = (j < 64) ? q[b * 64 + j] : 0.5f * ctx[b * 32 + (j - 64)];
  qc[t] = f2bf(v * LOG2E);                     // fold log2(e) for exp2 softmax
}

__global__ void prep_bias(const float* __restrict__ ts, const int* __restrict__ used,
                          float* __restrict__ bias) {
  int m = blockIdx.x * 256 + threadIdx.x;
  // exp2 domain: log2e*(0.3*decay) - SHIFT2 ; masked -> -1e9 (exp2 -> 0)
  bias[m] = used[m] ? (LOG2E * 0.3f * __expf(-0.1f * (1.0f - ts[m])) - SHIFT2) : -1e9f;
}

// K+context in MFMA B-fragment-linear order:
// kc2[g][c][lane][8], c = nt*3 + s; element = Kc[m = g*64+nt*16+(lane&15)]
//                                              [kk = s*32+(lane>>4)*8+j]
// -> every wave-level frag load is one dense, coalesced 1KB dwordx4.
__global__ void prep_kc2(const float* __restrict__ keys, const float* __restrict__ ctxs,
                         unsigned short* __restrict__ kc2) {
  __shared__ float lk[64][65];
  __shared__ float lx[64][33];
  const int g = blockIdx.x;          // 1024 groups of 64 keys
  const int t = threadIdx.x;
  const float* kb = keys + (size_t)g * 64 * 64;
  const float* xb = ctxs + (size_t)g * 64 * 32;
#pragma unroll
  for (int i = 0; i < 16; ++i) {
    int idx = i * 256 + t;
    lk[idx >> 6][idx & 63] = kb[idx];
  }
#pragma unroll
  for (int i = 0; i < 8; ++i) {
    int idx = i * 256 + t;
    lx[idx >> 5][idx & 31] = xb[idx];
  }
  __syncthreads();
  unsigned short* outp = kc2 + (size_t)g * 6144;
#pragma unroll
  for (int p = 0; p < 3; ++p) {
    int o = p * 2048 + t * 8;
    int c = o >> 9;                  // 0..11
    int lane = (o >> 3) & 63;
    int lq = lane >> 4, lcc = lane & 15;
    int nt = c / 3, s = c - nt * 3;
    int ml = nt * 16 + lcc;
    short8 v;
#pragma unroll
    for (int j = 0; j < 8; ++j) {
      int kk = s * 32 + lq * 8 + j;
      float f = (kk < 64) ? lk[ml][kk] : lx[ml][kk - 64];
      v[j] = (short)f2bf(f);
    }
    *reinterpret_cast<short8*>(outp + o) = v;
  }
}

// V in PV B-fragment-linear order:
// vt2[g][c2][lane][8], c2 = h*4 + nd; element = V[m = g*64+h*32+(lane>>4)*8+j]
//                                                [d = nd*16+(lane&15)]
__global__ void prep_vt2(const float* __restrict__ v, unsigned short* __restrict__ vt2) {
  __shared__ float lv[64][65];
  const int g = blockIdx.x;
  const int t = threadIdx.x;
  const float* vb = v + (size_t)g * 64 * 64;
#pragma unroll
  for (int i = 0; i < 16; ++i) {
    int idx = i * 256 + t;
    lv[idx >> 6][idx & 63] = vb[idx];
  }
  __syncthreads();
  unsigned short* outp = vt2 + (size_t)g * 4096;
#pragma unroll
  for (int p = 0; p < 2; ++p) {
    int o = p * 2048 + t * 8;
    int c2 = o >> 9;                 // 0..7
    int lane = (o >> 3) & 63;
    int lq = lane >> 4, lcc = lane & 15;
    int h = c2 >> 2, nd = c2 & 3;
    short8 w;
#pragma unroll
    for (int j = 0; j < 8; ++j)
      w[j] = (short)f2bf(lv[h * 32 + lq * 8 + j][nd * 16 + lcc]);
    *reinterpret_cast<short8*>(outp + o) = w;
  }
}

// ---- flash attention main kernel -------------------------------------------
// grid (NQT, NC); block 256 = 4 waves; each wave owns 32 q rows (2 A-frags).
// Fixed-shift softmax: P = exp2(S + bias'); partials combine linearly.

template<int NC>
__global__ __launch_bounds__(256, 3) void
flash_kernel(const unsigned short* __restrict__ qc,
             const unsigned short* __restrict__ kc2,
             const unsigned short* __restrict__ vt2,
             const float* __restrict__ bias,
             float* __restrict__ opart, float* __restrict__ lpart)
{
  constexpr int MC = M_TOT / NC;       // keys per block
  constexpr int NIT = MC / BN;
  __shared__ __align__(16) unsigned short pt[4][2][16][SP];  // per-wave P tiles
  const int qt    = blockIdx.x;
  const int chunk = blockIdx.y;
  const int tid   = threadIdx.x;
  const int w     = tid >> 6;
  const int lane  = tid & 63;
  const int lq    = lane >> 4;
  const int lc    = lane & 15;

  floatx4 zero; zero[0] = 0.f; zero[1] = 0.f; zero[2] = 0.f; zero[3] = 0.f;

  // Q fragments: rows qt*128 + w*32 + a*16 + lc
  short8 qf[2][3];
#pragma unroll
  for (int a = 0; a < 2; ++a) {
    const unsigned short* qrp = qc + (size_t)(qt * BQ + w * 32 + a * 16 + lc) * KD + lq * 8;
    qf[a][0] = *reinterpret_cast<const short8*>(qrp);
    qf[a][1] = *reinterpret_cast<const short8*>(qrp + 32);
    qf[a][2] = *reinterpret_cast<const short8*>(qrp + 64);
  }

  short8 ones;
#pragma unroll
  for (int i = 0; i < 8; ++i) ones[i] = (short)0x3F80;  // bf16 1.0

  const int g0 = chunk * (MC / 64);
  const unsigned short* kptr = kc2 + (size_t)g0 * 6144 + lane * 8;
  const unsigned short* vptr = vt2 + (size_t)g0 * 4096 + lane * 8;
  const float* bptr = bias + chunk * MC + lc;

  floatx4 o[2][4];
#pragma unroll
  for (int a = 0; a < 2; ++a)
#pragma unroll
    for (int nd = 0; nd < 4; ++nd) o[a][nd] = zero;
  floatx4 lacc[2] = {zero, zero};

#pragma unroll 1
  for (int it = 0; it < NIT; ++it) {
    // dense coalesced frag loads (each = 1KB per wave)
    short8 kf[12];
#pragma unroll
    for (int c = 0; c < 12; ++c)
      kf[c] = *reinterpret_cast<const short8*>(kptr + c * 512);
    short8 vf[8];
#pragma unroll
    for (int c = 0; c < 8; ++c)
      vf[c] = *reinterpret_cast<const short8*>(vptr + c * 512);
    float badj[4];
#pragma unroll
    for (int nt = 0; nt < 4; ++nt) badj[nt] = bptr[nt * 16];

    // S = Q*K^T, P = exp2(S + bias') -> LDS (C-layout)
#pragma unroll
    for (int a = 0; a < 2; ++a) {
#pragma unroll
      for (int nt = 0; nt < 4; ++nt) {
        floatx4 acc = zero;
        acc = mfma16(qf[a][0], kf[nt * 3 + 0], acc);
        acc = mfma16(qf[a][1], kf[nt * 3 + 1], acc);
        acc = mfma16(qf[a][2], kf[nt * 3 + 2], acc);
#pragma unroll
        for (int r = 0; r < 4; ++r) {
          float p = __builtin_amdgcn_exp2f(acc[r] + badj[nt]);
          pt[w][a][lq * 4 + r][nt * 16 + lc] = f2bf(p);
        }
      }
    }
    // P -> A-layout (same-wave DS ordering; no barrier needed)
#pragma unroll
    for (int a = 0; a < 2; ++a) {
      short8 pa0 = *reinterpret_cast<const short8*>(&pt[w][a][lc][lq * 8]);
      short8 pa1 = *reinterpret_cast<const short8*>(&pt[w][a][lc][32 + lq * 8]);
      lacc[a] = mfma16(pa0, ones, lacc[a]);
      lacc[a] = mfma16(pa1, ones, lacc[a]);
#pragma unroll
      for (int nd = 0; nd < 4; ++nd) {
        o[a][nd] = mfma16(pa0, vf[nd],     o[a][nd]);
        o[a][nd] = mfma16(pa1, vf[4 + nd], o[a][nd]);
      }
    }
    kptr += 12 * 512;
    vptr += 8 * 512;
    bptr += BN;
  }

  // epilogue: write partial O and l
  const int pb = qt * NC + chunk;
  float* op = opart + (size_t)pb * BQ * D_V;
#pragma unroll
  for (int a = 0; a < 2; ++a) {
    const int rbase = w * 32 + a * 16 + lq * 4;
#pragma unroll
    for (int nd = 0; nd < 4; ++nd)
#pragma unroll
      for (int r = 0; r < 4; ++r)
        op[(rbase + r) * D_V + nd * 16 + lc] = o[a][nd][r];
    if (lc == 0) {
      float* lp = lpart + (size_t)pb * BQ;
#pragma unroll
      for (int r = 0; r < 4; ++r) lp[rbase + r] = lacc[a][r];
    }
  }
}

// ---- final reduction --------------------------------------------------------

template<int NC>
__global__ void reduce_out(const float* __restrict__ opart, const float* __restrict__ lpart,
                           float* __restrict__ out) {
  int t = blockIdx.x * 256 + threadIdx.x;   // 262144 total
  int b = t >> 6, d = t & 63;
  int qt = b >> 7, r = b & 127;
  float os = 0.f, ls = 0.f;
#pragma unroll
  for (int c = 0; c < NC; ++c) {
    os += opart[((size_t)(qt * NC + c) * BQ + r) * D_V + d];
    ls += lpart[(size_t)(qt * NC + c) * BQ + r];
  }
  out[t] = os / ls;
}

// ---- launcher ---------------------------------------------------------------

template<int NC>
static void launch_all(const float* query, const float* context, const float* keys,
                       const float* values, const float* contexts, const float* ts,
                       const int* used, float* out, char* ws, hipStream_t stream) {
  unsigned short* qc  = (unsigned short*)ws;  ws += (size_t)B_TOT * KD * 2;        // 768 KB
  unsigned short* kc2 = (unsigned short*)ws;  ws += (size_t)M_TOT * KD * 2;        // 12.6 MB
  unsigned short* vt2 = (unsigned short*)ws;  ws += (size_t)D_V * M_TOT * 2;       // 8.4 MB
  float* bias  = (float*)ws;                  ws += (size_t)M_TOT * 4;             // 256 KB
  float* opart = (float*)ws;                  ws += (size_t)NC * B_TOT * D_V * 4;
  float* lpart = (float*)ws;

  prep_qc  <<<(B_TOT * KD) / 256, 256, 0, stream>>>(query, context, qc);
  prep_kc2 <<<M_TOT / 64,         256, 0, stream>>>(keys, contexts, kc2);
  prep_bias<<<M_TOT / 256,        256, 0, stream>>>(ts, used, bias);
  prep_vt2 <<<M_TOT / 64,         256, 0, stream>>>(values, vt2);

  dim3 grid(NQT, NC);
  flash_kernel<NC><<<grid, 256, 0, stream>>>(qc, kc2, vt2, bias, opart, lpart);

  reduce_out<NC><<<(B_TOT * D_V) / 256, 256, 0, stream>>>(opart, lpart, out);
}

extern "C" void kernel_launch(void* const* d_in, const int* in_sizes, int n_in,
                              void* d_out, int out_size, void* d_ws, size_t ws_size,
                              hipStream_t stream) {
  const float* query    = (const float*)d_in[0];
  const float* context  = (const float*)d_in[1];
  const float* keys     = (const float*)d_in[2];
  const float* values   = (const float*)d_in[3];
  const float* contexts = (const float*)d_in[4];
  const float* ts       = (const float*)d_in[5];
  const int*   used     = (const int*)d_in[6];
  float* out = (float*)d_out;
  char* ws = (char*)d_ws;

  const size_t fixed = (size_t)B_TOT * KD * 2 + (size_t)M_TOT * KD * 2 +
                       (size_t)D_V * M_TOT * 2 + (size_t)M_TOT * 4;
  const size_t need32 = fixed + 32ull * ((size_t)B_TOT * D_V * 4 + (size_t)B_TOT * 4);

  if (ws_size >= need32)
    launch_all<32>(query, context, keys, values, contexts, ts, used, out, ws, stream);
  else
    launch_all<16>(query, context, keys, values, contexts, ts, used, out, ws, stream);
}